// Round 16
// baseline (128.780 us; speedup 1.0000x reference)
//
#include <hip/hip_runtime.h>
#include <hip/hip_bf16.h>

#define SCOPE 63
#define BT 256
#define WAVES_PER_BLOCK 4
#define ROWS_PER_WAVE 32
#define TILE_ROWS 128
#define TILE_ELEMS (TILE_ROWS * SCOPE)   // 8064 floats = 32256 B per buffer
#define TILE_F4 (TILE_ELEMS / 4)         // 2016 float4
#define NOUT 32
#define TILES_PER_BLOCK 4                // 4096 tiles / 1024 blocks

// async global->LDS, 16B per lane; LDS dest is wave-uniform base + lane*16
#define GLL(gp, lp) __builtin_amdgcn_global_load_lds(                         \
    (const __attribute__((address_space(1))) void*)(gp),                      \
    (__attribute__((address_space(3))) void*)(lp), 16, 0, 0)

// ---------------------------------------------------------------------------
// Kernel 1: inverse filter g = IFFT( 1 / FFT(delta - f) ) in fp64. Negligible.
// ---------------------------------------------------------------------------
__global__ void compute_inverse_filter(const float* __restrict__ f,
                                       float* __restrict__ g) {
    __shared__ double hre[SCOPE];
    __shared__ double him[SCOPE];
    const double TWO_PI = 6.283185307179586476925286766559;
    int t = threadIdx.x;
    if (t < SCOPE) {
        double re = 0.0, im = 0.0;
        for (int n = 0; n < SCOPE; ++n) {
            double x = (n == 0 ? 1.0 : 0.0) - (double)f[n];
            double ang = -TWO_PI * (double)(t * n) / (double)SCOPE;
            re += x * cos(ang);
            im += x * sin(ang);
        }
        double d = re * re + im * im;
        hre[t] = re / d;
        him[t] = -im / d;
    }
    __syncthreads();
    if (t < SCOPE) {
        double acc = 0.0;
        for (int k = 0; k < SCOPE; ++k) {
            double ang = TWO_PI * (double)(k * t) / (double)SCOPE;
            acc += hre[k] * cos(ang) - him[k] * sin(ang);
        }
        g[t] = (float)(acc / (double)SCOPE);
    }
}

// ---------------------------------------------------------------------------
// Compile-time-unrolled helpers (static indices only -> SROA to registers).
// ---------------------------------------------------------------------------
template <int J0, int J1>
struct LoadSegStop {
    template <int J>
    struct Step {
        __device__ static inline void run(float (&d)[SCOPE], const float* p) {
            if constexpr (J >= J0) {
                Step<J - 1>::run(d, p);
                d[J] = p[J - J0];
            }
        }
    };
    __device__ static inline void run(float (&d)[SCOPE], const float* p) {
        Step<J1>::run(d, p);
    }
};

template <int M, int I>
struct TapRow {
    __device__ static inline void run(float (&acc)[NOUT], const float (&a)[SCOPE],
                                      float gm) {
        TapRow<M, I - 1>::run(acc, a, gm);
        acc[I] += gm * a[(I - M + SCOPE) % SCOPE];
    }
};
template <int M>
struct TapRow<M, -1> {
    __device__ static inline void run(float (&)[NOUT], const float (&)[SCOPE], float) {}
};

template <int M>
struct TapLoop {
    __device__ static inline void run(float (&acc)[NOUT], const float (&a)[SCOPE],
                                      const float* gs) {
        TapLoop<M - 1>::run(acc, a, gs);
        const float gm = gs[M];
        TapRow<M, NOUT - 1>::run(acc, a, gm);
    }
};
template <>
struct TapLoop<0> {
    __device__ static inline void run(float (&acc)[NOUT], const float (&a)[SCOPE],
                                      const float* gs) {
        const float g0 = gs[0];
#pragma unroll
        for (int i = 0; i < NOUT; ++i) acc[i] = g0 * a[i];
    }
};

template <int I>
struct StoreSeg {
    __device__ static inline void run(float* q, const float (&acc)[NOUT]) {
        StoreSeg<I - 1>::run(q, acc);
        q[I] = acc[I];
    }
};
template <>
struct StoreSeg<-1> {
    __device__ static inline void run(float*, const float (&)[NOUT]) {}
};

// ---------------------------------------------------------------------------
// Pipeline phases (forceinline; buf is always a STATIC array after inlining so
// ds_reads of one buffer provably don't alias the in-flight GLLs of the other)
// ---------------------------------------------------------------------------
__device__ __forceinline__ void stage_tile(const float* __restrict__ A,
                                           long long tile, float* buf, int tid) {
    const float4* g = (const float4*)(A + tile * (long long)TILE_ELEMS);
    float4* lb = (float4*)buf;
#pragma unroll
    for (int it = 0; it < 7; ++it)
        GLL(g + it * 256 + tid, lb + it * 256 + tid);
    if (tid < 224)
        GLL(g + 1792 + tid, lb + 1792 + tid);
}

__device__ __forceinline__ void compute_tile(float* buf, const float* gs,
                                             int w, int r, int h) {
    // rotated row load: a_rot[k] = row[(32h + k) mod 63], 2 bases, static offs
    float* myrow = buf + (w * ROWS_PER_WAVE + r) * SCOPE;
    const float* q1 = myrow + 32 * h;        // j in [0,31)
    const float* q2 = myrow + 31 - 31 * h;   // j in [31,63)
    float a[SCOPE];
    LoadSegStop<0, 30>::run(a, q1);
    LoadSegStop<31, 62>::run(a, q2);

    float acc[NOUT];
    TapLoop<SCOPE - 1>::run(acc, a, gs);

    float* qo = myrow + 32 * h;
    StoreSeg<30>::run(qo, acc);
    if (h == 0) qo[31] = acc[31];   // half 1 has only 31 outputs
}

__device__ __forceinline__ void store_tile(float* __restrict__ O, long long tile,
                                           const float* buf, int tid) {
    const float4* lb = (const float4*)buf;
    float4* g = (float4*)(O + tile * (long long)TILE_ELEMS);
#pragma unroll
    for (int it = 0; it < 7; ++it)
        g[it * 256 + tid] = lb[it * 256 + tid];
    if (tid < 224)
        g[1792 + tid] = lb[1792 + tid];
}

// ---------------------------------------------------------------------------
// Kernel 2: double-buffered pipeline. Each block owns 4 tiles of 128 rows;
// tile t+1's global_load_lds fly under tile t's 2016 FMAs (T3 2-phase).
// bufA/bufB are distinct static arrays (runtime-indexed buf[cur] would make
// ds_reads MayAlias the async LDS writes -> compiler-inserted vmcnt drain).
// Lane mapping r=l&31, h=l>>5: 32 distinct banks per LDS phase (r15: 0 confl).
// ---------------------------------------------------------------------------
__global__ void __launch_bounds__(BT)
circ_conv_kernel(const float* __restrict__ A,
                 const float* __restrict__ G,
                 float* __restrict__ O) {
    __shared__ __align__(16) float bufA[TILE_ELEMS];
    __shared__ __align__(16) float bufB[TILE_ELEMS];
    __shared__ float gs[SCOPE];

    const int tid = threadIdx.x;
    const int w   = tid >> 6;
    const int l   = tid & 63;
    const int r   = l & 31;
    const int h   = l >> 5;

    if (tid < SCOPE) gs[tid] = G[tid];

    const long long tile0 = (long long)blockIdx.x * TILES_PER_BLOCK;

    stage_tile(A, tile0, bufA, tid);
    __syncthreads();   // auto-drains vmcnt: bufA ready, gs visible

#pragma unroll
    for (int tp = 0; tp < TILES_PER_BLOCK / 2; ++tp) {
        const long long tA = tile0 + tp * 2;

        // ---- phase A: prefetch B, compute A ----
        stage_tile(A, tA + 1, bufB, tid);
        compute_tile(bufA, gs, w, r, h);
        __syncthreads();              // outputs visible; bufB staged (drain)
        store_tile(O, tA, bufA, tid);
        __syncthreads();              // bufA free for reuse

        // ---- phase B: prefetch A, compute B ----
        if (tp * 2 + 2 < TILES_PER_BLOCK)
            stage_tile(A, tA + 2, bufA, tid);
        compute_tile(bufB, gs, w, r, h);
        __syncthreads();
        store_tile(O, tA + 1, bufB, tid);
        __syncthreads();
    }
}

// ---------------------------------------------------------------------------
extern "C" void kernel_launch(void* const* d_in, const int* in_sizes, int n_in,
                              void* d_out, int out_size, void* d_ws, size_t ws_size,
                              hipStream_t stream) {
    const float* activations = (const float*)d_in[0];
    const float* filt        = (const float*)d_in[1];
    float* out               = (float*)d_out;
    float* g                 = (float*)d_ws;   // 63 floats of scratch

    hipLaunchKernelGGL(compute_inverse_filter, dim3(1), dim3(64), 0, stream,
                       filt, g);

    const long long total = (long long)in_sizes[0];
    const long long rows  = total / SCOPE;                         // 524288
    const int blocks = (int)(rows / (TILE_ROWS * TILES_PER_BLOCK)); // 1024, exact

    hipLaunchKernelGGL(circ_conv_kernel, dim3(blocks), dim3(BT), 0,
                       stream, activations, g, out);
}

// Round 17
// 105.952 us; speedup vs baseline: 1.2155x; 1.2155x over previous
//
#include <hip/hip_runtime.h>
#include <hip/hip_bf16.h>

#define SCOPE 63
#define BLOCK_THREADS 256
#define WAVES_PER_BLOCK 4
#define ROWS_PER_WAVE 32
#define ROWS_PER_BLOCK 128
#define TILE_ELEMS (ROWS_PER_BLOCK * SCOPE)   // 8064 floats = 32256 B
#define NOUT 32                                // outputs per lane (half-row)

// async global->LDS, 16B per lane; LDS dest is wave-uniform base + lane*16
#define GLL(gp, lp) __builtin_amdgcn_global_load_lds(                         \
    (const __attribute__((address_space(1))) void*)(gp),                      \
    (__attribute__((address_space(3))) void*)(lp), 16, 0, 0)

// ---------------------------------------------------------------------------
// Kernel 1: inverse filter g = IFFT( 1 / FFT(delta - f) ) in fp64. Negligible.
// ---------------------------------------------------------------------------
__global__ void compute_inverse_filter(const float* __restrict__ f,
                                       float* __restrict__ g) {
    __shared__ double hre[SCOPE];
    __shared__ double him[SCOPE];
    const double TWO_PI = 6.283185307179586476925286766559;
    int t = threadIdx.x;
    if (t < SCOPE) {
        double re = 0.0, im = 0.0;
        for (int n = 0; n < SCOPE; ++n) {
            double x = (n == 0 ? 1.0 : 0.0) - (double)f[n];
            double ang = -TWO_PI * (double)(t * n) / (double)SCOPE;
            re += x * cos(ang);
            im += x * sin(ang);
        }
        double d = re * re + im * im;
        hre[t] = re / d;
        him[t] = -im / d;
    }
    __syncthreads();
    if (t < SCOPE) {
        double acc = 0.0;
        for (int k = 0; k < SCOPE; ++k) {
            double ang = TWO_PI * (double)(k * t) / (double)SCOPE;
            acc += hre[k] * cos(ang) - him[k] * sin(ang);
        }
        g[t] = (float)(acc / (double)SCOPE);
    }
}

// ---------------------------------------------------------------------------
// Compile-time-unrolled helpers (static indices only -> SROA to registers).
// ---------------------------------------------------------------------------
template <int J0, int J1>
struct LoadSegStop {
    template <int J>
    struct Step {
        __device__ static inline void run(float (&d)[SCOPE], const float* p) {
            if constexpr (J >= J0) {
                Step<J - 1>::run(d, p);
                d[J] = p[J - J0];
            }
        }
    };
    __device__ static inline void run(float (&d)[SCOPE], const float* p) {
        Step<J1>::run(d, p);
    }
};

template <int M, int I>
struct TapRow {
    __device__ static inline void run(float (&acc)[NOUT], const float (&a)[SCOPE],
                                      float gm) {
        TapRow<M, I - 1>::run(acc, a, gm);
        acc[I] += gm * a[(I - M + SCOPE) % SCOPE];
    }
};
template <int M>
struct TapRow<M, -1> {
    __device__ static inline void run(float (&)[NOUT], const float (&)[SCOPE], float) {}
};

template <int M>
struct TapLoop {
    __device__ static inline void run(float (&acc)[NOUT], const float (&a)[SCOPE],
                                      const float* gs) {
        TapLoop<M - 1>::run(acc, a, gs);
        const float gm = gs[M];
        TapRow<M, NOUT - 1>::run(acc, a, gm);
    }
};
template <>
struct TapLoop<0> {   // M = 0 initializes the accumulators
    __device__ static inline void run(float (&acc)[NOUT], const float (&a)[SCOPE],
                                      const float* gs) {
        const float g0 = gs[0];
#pragma unroll
        for (int i = 0; i < NOUT; ++i) acc[i] = g0 * a[i];
    }
};

template <int I>
struct StoreSeg {
    __device__ static inline void run(float* q, const float (&acc)[NOUT]) {
        StoreSeg<I - 1>::run(q, acc);
        q[I] = acc[I];
    }
};
template <>
struct StoreSeg<-1> {
    __device__ static inline void run(float*, const float (&)[NOUT]) {}
};

// ---------------------------------------------------------------------------
// Kernel 2: r15 structure (best known: 99 us) with ONE change — staging via
// global_load_lds width=16 (async HBM->LDS, no VGPR round-trip; single vmcnt
// drain at the barrier instead of per-load waits).
//
// 256 threads = 4 waves; 128 rows/block; lane l: r=l&31, h=l>>5 (conflict-free
// LDS phases, verified 0 conflicts r15). Rotated-register row, 63-tap conv,
// outputs through LDS for coalesced float4 stores.
// ---------------------------------------------------------------------------
__global__ void __launch_bounds__(BLOCK_THREADS)
circ_conv_kernel(const float* __restrict__ A,
                 const float* __restrict__ G,
                 float* __restrict__ O) {
    __shared__ __align__(16) float tile[TILE_ELEMS];
    __shared__ float gs[SCOPE];

    const int tid = threadIdx.x;
    const int w   = tid >> 6;        // wave in block
    const int l   = tid & 63;        // lane in wave
    const int r   = l & 31;          // row within wave's 32
    const int h   = l >> 5;          // output half

    const long long row0 = (long long)blockIdx.x * ROWS_PER_BLOCK;
    const float* __restrict__ src = A + row0 * SCOPE;
    float* __restrict__ dst       = O + row0 * SCOPE;

    if (tid < SCOPE) gs[tid] = G[tid];

    // ---- stage 128 rows (2016 float4) via async global->LDS ----
    const float4* src4 = (const float4*)src;
    float4* w4 = (float4*)tile;
#pragma unroll
    for (int it = 0; it < 7; ++it)
        GLL(src4 + it * 256 + tid, w4 + it * 256 + tid);
    if (tid < 224)
        GLL(src4 + 1792 + tid, w4 + 1792 + tid);

    __syncthreads();   // drains vmcnt: tile ready; gs visible

    // ---- rotated row load: 2 runtime bases, all-static offsets ----
    float* myrow = tile + (w * ROWS_PER_WAVE + r) * SCOPE;
    const float* q1 = myrow + 32 * h;        // j in [0,31)
    const float* q2 = myrow + 31 - 31 * h;   // j in [31,63)
    float a[SCOPE];
    LoadSegStop<0, 30>::run(a, q1);
    LoadSegStop<31, 62>::run(a, q2);

    // ---- 63-tap convolution into 32 register accumulators ----
    float acc[NOUT];
    TapLoop<SCOPE - 1>::run(acc, a, gs);

    // ---- write outputs back to own row region (conflict-free per phase) ----
    float* qo = myrow + 32 * h;
    StoreSeg<30>::run(qo, acc);
    if (h == 0) qo[31] = acc[31];   // half 1 has only 31 outputs

    __syncthreads();

    // ---- coalesced store ----
    float4* dst4 = (float4*)dst;
#pragma unroll
    for (int it = 0; it < 7; ++it)
        dst4[it * 256 + tid] = w4[it * 256 + tid];
    if (tid < 224)
        dst4[1792 + tid] = w4[1792 + tid];
}

// ---------------------------------------------------------------------------
extern "C" void kernel_launch(void* const* d_in, const int* in_sizes, int n_in,
                              void* d_out, int out_size, void* d_ws, size_t ws_size,
                              hipStream_t stream) {
    const float* activations = (const float*)d_in[0];
    const float* filt        = (const float*)d_in[1];
    float* out               = (float*)d_out;
    float* g                 = (float*)d_ws;   // 63 floats of scratch

    hipLaunchKernelGGL(compute_inverse_filter, dim3(1), dim3(64), 0, stream,
                       filt, g);

    const long long total = (long long)in_sizes[0];
    const long long rows  = total / SCOPE;                 // 524288
    const int blocks      = (int)(rows / ROWS_PER_BLOCK);  // 4096, exact

    hipLaunchKernelGGL(circ_conv_kernel, dim3(blocks), dim3(BLOCK_THREADS), 0,
                       stream, activations, g, out);
}